// Round 1
// 129.752 us; speedup vs baseline: 1.0572x; 1.0572x over previous
//
#include <hip/hip_runtime.h>
#include <math.h>

#define R_ROUTES 1152
#define CIN 8
#define COUT 16
#define BATCH 512
#define NCAPS 10
#define NUM_ROUNDS 3

typedef __fp16 h2 __attribute__((ext_vector_type(2)));
union U32H2 { unsigned int u; h2 h; };

__device__ __forceinline__ unsigned int pkrtz(float lo, float hi) {
    U32H2 v; v.h = __builtin_amdgcn_cvt_pkrtz(lo, hi);   // v_cvt_pkrtz_f16_f32
    return v.u;
}
__device__ __forceinline__ h2 as_h2(unsigned int u) { U32H2 v; v.u = u; return v.h; }
__device__ __forceinline__ float f_lo(unsigned int u) { return (float)as_h2(u).x; }
__device__ __forceinline__ float f_hi(unsigned int u) { return (float)as_h2(u).y; }
__device__ __forceinline__ float dot2(unsigned int p, unsigned int s, float c) {
    return __builtin_amdgcn_fdot2(as_h2(p), as_h2(s), c, false);  // v_dot2_f32_f16
}

// ---------------- cross-lane sums on the VALU pipe (DPP / permlane) ----------
// Replaces __shfl_xor (ds_swizzle -> LDS pipe) with DPP adds + gfx950
// v_permlane{16,32}_swap_b32.  Row-rotate levels scramble WHICH lane holds
// which partial group, but every writer lane still holds a disjoint full
// cover, and all consumers sum over all writers -> order-only change.
#define DPP_XOR1 0xB1   // quad_perm(1,0,3,2)
#define DPP_XOR2 0x4E   // quad_perm(2,3,0,1)
#define DPP_ROR4 0x124  // row_ror:4  (preserves lane mod 4 -> oq-safe)
#define DPP_ROR8 0x128  // row_ror:8
template<int CTRL>
__device__ __forceinline__ float dpp_add(float v) {
    int d = __builtin_amdgcn_update_dpp(0, __float_as_int(v), CTRL, 0xf, 0xf, false);
    return v + __int_as_float(d);
}
__device__ __forceinline__ float p16_add(float v) {   // v + (value from lane^16)
    float a = v, b = v;
    asm("v_permlane16_swap_b32 %0, %1" : "+v"(a), "+v"(b));
    return a + b;
}
__device__ __forceinline__ float p32_add(float v) {   // v + (value from lane^32)
    float a = v, b = v;
    asm("v_permlane32_swap_b32 %0, %1" : "+v"(a), "+v"(b));
    return a + b;
}
__device__ __forceinline__ float wave_sum64(float v) {  // full-wave sum, all lanes
    v = dpp_add<DPP_XOR1>(v);
    v = dpp_add<DPP_XOR2>(v);
    v = dpp_add<DPP_ROR4>(v);
    v = dpp_add<DPP_ROR8>(v);
    v = p16_add(v);
    return p32_add(v);
}

// Swizzled 16-B-unit index for (row r, half h): bijection within each 128-B
// group, spreads consecutive-r b128 reads over all 8 bank groups (R5-verified).
__device__ __forceinline__ int sunit(int r, int h) {
    return (2 * r + h) ^ ((r >> 2) & 7);
}

__device__ __forceinline__ float sq16(float4 a, float4 b, float4 c, float4 d) {
    float sn = a.x * a.x;
    sn = fmaf(a.y, a.y, sn); sn = fmaf(a.z, a.z, sn); sn = fmaf(a.w, a.w, sn);
    sn = fmaf(b.x, b.x, sn); sn = fmaf(b.y, b.y, sn); sn = fmaf(b.z, b.z, sn);
    sn = fmaf(b.w, b.w, sn);
    sn = fmaf(c.x, c.x, sn); sn = fmaf(c.y, c.y, sn); sn = fmaf(c.z, c.z, sn);
    sn = fmaf(c.w, c.w, sn);
    sn = fmaf(d.x, d.x, sn); sn = fmaf(d.y, d.y, sn); sn = fmaf(d.z, d.z, sn);
    sn = fmaf(d.w, d.w, sn);
    return sn;
}

// ---------------- Kernel 1: pack W (always) and optionally x to f16 pairs.
// Blocks < 720:   W fp32 [n][r][i][o] -> Wp [n][r][o][i/2]  (256 B / row)
// Blocks >= 720:  x fp32 [b][r][i]    -> Xp [b][r] uint4 (8 halves, 16 B)
extern "C" __global__ void __launch_bounds__(256)
pack_wx(const float* __restrict__ W, const float* __restrict__ x,
        unsigned int* __restrict__ Wp, uint4* __restrict__ Xp)
{
    const int blk = blockIdx.x;
    if (blk < 720) {
        const int tau = blk * 256 + threadIdx.x;           // one thread per (n,r,o)
        const int o = tau & 15;
        const int nr = tau >> 4;
        const float* __restrict__ src = W + (size_t)nr * 128 + o;
        uint4 u;
        u.x = pkrtz(src[0],  src[16]);    // (i0,i1)
        u.y = pkrtz(src[32], src[48]);    // (i2,i3)
        u.z = pkrtz(src[64], src[80]);    // (i4,i5)
        u.w = pkrtz(src[96], src[112]);   // (i6,i7)
        *(uint4*)(Wp + (size_t)tau * 4) = u;
    } else {
        const int idx = (blk - 720) * 256 + threadIdx.x;   // one thread per (b,r)
        const float4 a = *(const float4*)(x + (size_t)idx * 8);
        const float4 b = *(const float4*)(x + (size_t)idx * 8 + 4);
        uint4 u;
        u.x = pkrtz(a.x, a.y);
        u.y = pkrtz(a.z, a.w);
        u.z = pkrtz(b.x, b.y);
        u.w = pkrtz(b.z, b.w);
        Xp[idx] = u;
    }
}

// ---------------- Main: 512 threads per (n, b-pair), f16 everywhere.
// v10 changes vs v9: (1) all shuffle reductions moved to DPP/permlane (VALU
// pipe, frees the LDS pipe which was ~45% occupied); (2) Phase A ping-pong
// register prefetch hides L2/L3 load latency; (3) x consumed pre-packed f16
// (XP=true) -> no per-n re-pkrtz; (4) s-vector read as 4x ds_read_b128 into
// registers, sn/factor/svp computed from regs; (5) colsum finish done by one
// full wave (8 reads + 2 permlane levels) instead of 16 threads x 32 reads.
template<bool XP>
__global__ void __launch_bounds__(512, 4)
capsule_routing_v10(const float* __restrict__ x,
                    const unsigned int* __restrict__ Wp,
                    const uint4* __restrict__ Xp,
                    float* __restrict__ out)
{
    __shared__ __align__(16) unsigned int pbuf[2 * R_ROUTES * 8]; // 73728 B priors
    __shared__ __align__(16) float wred[16 * 16];                 // 1024 B
    __shared__ __align__(16) float red[2 * 32 * 20];              // 5120 B
    __shared__ float sred[2 * 4];
    __shared__ __align__(16) float sv[2 * 16];

    const int blk = blockIdx.x;                      // n-major: Wp[n] L2-resident
    const int n = blk >> 8;
    const int bp = blk & 255;
    const int t = threadIdx.x;

    const unsigned int* __restrict__ Wn = Wp + (size_t)n * (R_ROUTES * 64);

    // ---------------- Phase A: priors (dot2) + pass-0 colsums, prefetched
    float cs[2][4] = {{0.f, 0.f, 0.f, 0.f}, {0.f, 0.f, 0.f, 0.f}};
    {
        const int q = t >> 2;                        // 0..127
        const int oq = t & 3;
        const int subw = (oq & 1) * 2;
        const int hq = oq >> 1;

        const float* __restrict__ x0 = x + (size_t)(2 * bp) * (R_ROUTES * CIN);
        const float* __restrict__ x1 = x0 + R_ROUTES * CIN;
        const uint4* __restrict__ xq0 = Xp + (size_t)(2 * bp) * R_ROUTES;
        const uint4* __restrict__ xq1 = xq0 + R_ROUTES;

        uint4 wA0, wA1, wA2, wA3, wB0, wB1, wB2, wB3;
        uint4 xA0, xA1, xB0, xB1;                    // packed h2 x rows (b0,b1)
        float4 gA0, gA1, gA2, gA3, gB0, gB1, gB2, gB3; // fallback raw x

        auto loadW = [&](int it, uint4& a0, uint4& a1, uint4& a2, uint4& a3) {
            const unsigned int* wb = Wn + (size_t)(it * 128 + q) * 64 + oq * 4;
            a0 = *(const uint4*)(wb + 0);            // o = oq
            a1 = *(const uint4*)(wb + 16);           // o = oq+4
            a2 = *(const uint4*)(wb + 32);           // o = oq+8
            a3 = *(const uint4*)(wb + 48);           // o = oq+12
        };
        auto loadX = [&](int it, uint4& a, uint4& b,
                         float4& g0, float4& g1, float4& g2, float4& g3) {
            const int r = it * 128 + q;
            if constexpr (XP) {
                a = xq0[r];
                b = xq1[r];
            } else {
                g0 = *(const float4*)(x0 + r * 8);
                g1 = *(const float4*)(x0 + r * 8 + 4);
                g2 = *(const float4*)(x1 + r * 8);
                g3 = *(const float4*)(x1 + r * 8 + 4);
            }
        };
        auto packX = [&](uint4& a, uint4& b,
                         float4 g0, float4 g1, float4 g2, float4 g3) {
            if constexpr (!XP) {
                a.x = pkrtz(g0.x, g0.y); a.y = pkrtz(g0.z, g0.w);
                a.z = pkrtz(g1.x, g1.y); a.w = pkrtz(g1.z, g1.w);
                b.x = pkrtz(g2.x, g2.y); b.y = pkrtz(g2.z, g2.w);
                b.z = pkrtz(g3.x, g3.y); b.w = pkrtz(g3.z, g3.w);
            }
        };
        auto compute = [&](int it, uint4 w0, uint4 w1, uint4 w2, uint4 w3,
                           uint4 xa, uint4 xb) {
            const int r = it * 128 + q;
            {   // batch 0
                const float p0 = dot2(w0.w, xa.w, dot2(w0.z, xa.z, dot2(w0.y, xa.y, dot2(w0.x, xa.x, 0.f))));
                const float p1 = dot2(w1.w, xa.w, dot2(w1.z, xa.z, dot2(w1.y, xa.y, dot2(w1.x, xa.x, 0.f))));
                const float p2 = dot2(w2.w, xa.w, dot2(w2.z, xa.z, dot2(w2.y, xa.y, dot2(w2.x, xa.x, 0.f))));
                const float p3 = dot2(w3.w, xa.w, dot2(w3.z, xa.z, dot2(w3.y, xa.y, dot2(w3.x, xa.x, 0.f))));
                cs[0][0] += p0; cs[0][1] += p1; cs[0][2] += p2; cs[0][3] += p3;
                uint2 u; u.x = pkrtz(p0, p1); u.y = pkrtz(p2, p3);
                *(uint2*)(pbuf + sunit(r, hq) * 4 + subw) = u;
            }
            {   // batch 1
                const float p0 = dot2(w0.w, xb.w, dot2(w0.z, xb.z, dot2(w0.y, xb.y, dot2(w0.x, xb.x, 0.f))));
                const float p1 = dot2(w1.w, xb.w, dot2(w1.z, xb.z, dot2(w1.y, xb.y, dot2(w1.x, xb.x, 0.f))));
                const float p2 = dot2(w2.w, xb.w, dot2(w2.z, xb.z, dot2(w2.y, xb.y, dot2(w2.x, xb.x, 0.f))));
                const float p3 = dot2(w3.w, xb.w, dot2(w3.z, xb.z, dot2(w3.y, xb.y, dot2(w3.x, xb.x, 0.f))));
                cs[1][0] += p0; cs[1][1] += p1; cs[1][2] += p2; cs[1][3] += p3;
                uint2 u; u.x = pkrtz(p0, p1); u.y = pkrtz(p2, p3);
                *(uint2*)(pbuf + R_ROUTES * 8 + sunit(r, hq) * 4 + subw) = u;
            }
        };

        // ping-pong: loads for it+1 issue before compute(it) -> ~1 full
        // compute stage (x4 waves) of latency cover, no rotation movs.
        loadW(0, wA0, wA1, wA2, wA3);
        loadX(0, xA0, xA1, gA0, gA1, gA2, gA3);
        #pragma unroll 1
        for (int it = 0; it < 8; it += 2) {
            loadW(it + 1, wB0, wB1, wB2, wB3);
            loadX(it + 1, xB0, xB1, gB0, gB1, gB2, gB3);
            packX(xA0, xA1, gA0, gA1, gA2, gA3);
            compute(it, wA0, wA1, wA2, wA3, xA0, xA1);
            loadW(it + 2, wA0, wA1, wA2, wA3);
            loadX(it + 2, xA0, xA1, gA0, gA1, gA2, gA3);
            packX(xB0, xB1, gB0, gB1, gB2, gB3);
            compute(it + 1, wB0, wB1, wB2, wB3, xB0, xB1);
        }
        packX(xA0, xA1, gA0, gA1, gA2, gA3);
        compute(8, wA0, wA1, wA2, wA3, xA0, xA1);

        // pass-0 reduce over same-oq lanes: 4 levels, all on VALU
        #pragma unroll
        for (int b = 0; b < 2; ++b)
            #pragma unroll
            for (int j = 0; j < 4; ++j) {
                float v = cs[b][j];
                v = dpp_add<DPP_ROR4>(v);
                v = dpp_add<DPP_ROR8>(v);
                v = p16_add(v);
                v = p32_add(v);
                cs[b][j] = v;
            }
        if ((t & 63) < 4) {                          // lane oq of each wave writes
            const int w = t >> 6;
            *(float4*)(wred + (w * 2 + 0) * 16 + 4 * oq) =
                make_float4(cs[0][0], cs[0][1], cs[0][2], cs[0][3]);
            *(float4*)(wred + (w * 2 + 1) * 16 + 4 * oq) =
                make_float4(cs[1][0], cs[1][1], cs[1][2], cs[1][3]);
        }
    }
    __syncthreads();                                 // barA1 (also pbuf ready)

    // ---------------- Phase B setup
    const int half = t >> 8;
    const int tt = t & 255;
    unsigned int* __restrict__ pb = pbuf + half * (R_ROUTES * 8);
    float* __restrict__ redh = red + half * (32 * 20);
    float* __restrict__ sredh = sred + half * 4;
    float* __restrict__ svh = sv + half * 16;        // permuted order end-to-end

    if (tt < 64) {                                   // one full wave per half
        const int k = tt & 15, wg = tt >> 4;
        float s = wred[(wg * 2 + half) * 16 + k] + wred[((wg + 4) * 2 + half) * 16 + k];
        s = p16_add(s);
        s = p32_add(s);
        if (tt < 16) svh[tt] = s * (1.0f / (float)R_ROUTES);
    }
    __syncthreads();                                 // barA2

    float4 s0 = *(const float4*)(svh + 0);
    float4 s1 = *(const float4*)(svh + 4);
    float4 s2 = *(const float4*)(svh + 8);
    float4 s3 = *(const float4*)(svh + 12);
    float sn = sq16(s0, s1, s2, s3);
    float factor = sn / ((1.0f + sn) * sqrtf(sn));

    const int nr = (tt < 128) ? 5 : 4;               // wave-uniform
    float bl[5] = {0.f, 0.f, 0.f, 0.f, 0.f};

    // ---------------- passes 1..2: fused logit-update + exp + weighted sum
    #pragma unroll 1
    for (int pass = 1; pass < NUM_ROUNDS; ++pass) {
        unsigned int svp[8];
        svp[0] = pkrtz(s0.x, s0.y); svp[1] = pkrtz(s0.z, s0.w);
        svp[2] = pkrtz(s1.x, s1.y); svp[3] = pkrtz(s1.z, s1.w);
        svp[4] = pkrtz(s2.x, s2.y); svp[5] = pkrtz(s2.z, s2.w);
        svp[6] = pkrtz(s3.x, s3.y); svp[7] = pkrtz(s3.z, s3.w);
        float acc[16];
        #pragma unroll
        for (int o = 0; o < 16; ++o) acc[o] = 0.f;
        float es = 0.f;

        #pragma unroll
        for (int k = 0; k < 5; ++k) {
            if (k < nr) {
                const int r = tt + (k << 8);
                const uint4 a = *(const uint4*)(pb + sunit(r, 0) * 4);
                const uint4 c = *(const uint4*)(pb + sunit(r, 1) * 4);
                float d = 0.f;
                d = dot2(a.x, svp[0], d);
                d = dot2(a.y, svp[1], d);
                d = dot2(a.z, svp[2], d);
                d = dot2(a.w, svp[3], d);
                d = dot2(c.x, svp[4], d);
                d = dot2(c.y, svp[5], d);
                d = dot2(c.z, svp[6], d);
                d = dot2(c.w, svp[7], d);
                bl[k] = fmaf(factor, d, bl[k]);
                const float e = __expf(bl[k]);
                es += e;
                acc[0]  = fmaf(e, f_lo(a.x), acc[0]);
                acc[1]  = fmaf(e, f_hi(a.x), acc[1]);
                acc[2]  = fmaf(e, f_lo(a.y), acc[2]);
                acc[3]  = fmaf(e, f_hi(a.y), acc[3]);
                acc[4]  = fmaf(e, f_lo(a.z), acc[4]);
                acc[5]  = fmaf(e, f_hi(a.z), acc[5]);
                acc[6]  = fmaf(e, f_lo(a.w), acc[6]);
                acc[7]  = fmaf(e, f_hi(a.w), acc[7]);
                acc[8]  = fmaf(e, f_lo(c.x), acc[8]);
                acc[9]  = fmaf(e, f_hi(c.x), acc[9]);
                acc[10] = fmaf(e, f_lo(c.y), acc[10]);
                acc[11] = fmaf(e, f_hi(c.y), acc[11]);
                acc[12] = fmaf(e, f_lo(c.z), acc[12]);
                acc[13] = fmaf(e, f_hi(c.z), acc[13]);
                acc[14] = fmaf(e, f_lo(c.w), acc[14]);
                acc[15] = fmaf(e, f_hi(c.w), acc[15]);
            }
        }
        es = wave_sum64(es);
        if ((t & 63) == 0) sredh[tt >> 6] = es;

        // 8-lane pre-reduce on VALU (DPP) -> 32 LDS writers per half
        #pragma unroll
        for (int o = 0; o < 16; ++o) {
            float v = acc[o];
            v = dpp_add<DPP_XOR1>(v);
            v = dpp_add<DPP_XOR2>(v);
            v = dpp_add<DPP_ROR4>(v);                // writers get disjoint 8-covers
            acc[o] = v;
        }
        if ((tt & 7) == 0) {
            float* dst = redh + (tt >> 3) * 20;      // 80-B stride: conflict-free b128
            *(float4*)(dst + 0)  = make_float4(acc[0],  acc[1],  acc[2],  acc[3]);
            *(float4*)(dst + 4)  = make_float4(acc[4],  acc[5],  acc[6],  acc[7]);
            *(float4*)(dst + 8)  = make_float4(acc[8],  acc[9],  acc[10], acc[11]);
            *(float4*)(dst + 12) = make_float4(acc[12], acc[13], acc[14], acc[15]);
        }
        __syncthreads();                             // bar1

        if (tt < 64) {                               // one full wave per half
            const int k = tt & 15, wg = tt >> 4;
            float s = 0.f;
            #pragma unroll
            for (int i = 0; i < 8; ++i) s += redh[(wg * 8 + i) * 20 + k];
            s = p16_add(s);
            s = p32_add(s);
            if (tt < 16) {
                const float Z = sredh[0] + sredh[1] + sredh[2] + sredh[3];
                svh[tt] = s / Z;
            }
        }
        __syncthreads();                             // bar2

        s0 = *(const float4*)(svh + 0);
        s1 = *(const float4*)(svh + 4);
        s2 = *(const float4*)(svh + 8);
        s3 = *(const float4*)(svh + 12);
        sn = sq16(s0, s1, s2, s3);
        factor = sn / ((1.0f + sn) * sqrtf(sn));
    }

    if (tt < 16) {
        const int o = (tt >> 2) + ((tt & 3) << 2);   // un-permute P[tt]
        out[((size_t)n * BATCH + 2 * bp + half) * COUT + o] = factor * svh[tt];
    }
}

extern "C" void kernel_launch(void* const* d_in, const int* in_sizes, int n_in,
                              void* d_out, int out_size, void* d_ws, size_t ws_size,
                              hipStream_t stream) {
    const float* x = (const float*)d_in[0];   // [512, 1152, 8] fp32
    const float* W = (const float*)d_in[1];   // [10, 1152, 8, 16] fp32
    float* out = (float*)d_out;               // [10, 512, 1, 1, 16] fp32

    unsigned int* Wp = (unsigned int*)d_ws;   // 2,949,120 B f16-packed W
    const size_t WPB = (size_t)NCAPS * R_ROUTES * COUT * 16;          // 2,949,120
    const size_t XPB = (size_t)BATCH * R_ROUTES * 16;                 // 9,437,184
    uint4* Xp = (uint4*)((char*)d_ws + WPB);

    if (ws_size >= WPB + XPB) {
        pack_wx<<<dim3(720 + 2304), dim3(256), 0, stream>>>(W, x, Wp, Xp);
        capsule_routing_v10<true><<<dim3(NCAPS * (BATCH / 2)), dim3(512), 0, stream>>>(x, Wp, Xp, out);
    } else {
        pack_wx<<<dim3(720), dim3(256), 0, stream>>>(W, x, Wp, Xp);
        capsule_routing_v10<false><<<dim3(NCAPS * (BATCH / 2)), dim3(512), 0, stream>>>(x, Wp, Xp, out);
    }
}

// Round 6
// 128.265 us; speedup vs baseline: 1.0695x; 1.0116x over previous
//
#include <hip/hip_runtime.h>
#include <math.h>

#define R_ROUTES 1152
#define CIN 8
#define COUT 16
#define BATCH 512
#define NCAPS 10
#define NUM_ROUNDS 3

typedef __fp16 h2 __attribute__((ext_vector_type(2)));
union U32H2 { unsigned int u; h2 h; };

__device__ __forceinline__ unsigned int pkrtz(float lo, float hi) {
    U32H2 v; v.h = __builtin_amdgcn_cvt_pkrtz(lo, hi);   // v_cvt_pkrtz_f16_f32
    return v.u;
}
__device__ __forceinline__ h2 as_h2(unsigned int u) { U32H2 v; v.u = u; return v.h; }
__device__ __forceinline__ float f_lo(unsigned int u) { return (float)as_h2(u).x; }
__device__ __forceinline__ float f_hi(unsigned int u) { return (float)as_h2(u).y; }
__device__ __forceinline__ float dot2(unsigned int p, unsigned int s, float c) {
    return __builtin_amdgcn_fdot2(as_h2(p), as_h2(s), c, false);  // v_dot2_f32_f16
}

// ---------------- cross-lane sums on the VALU pipe (DPP / permlane) ----------
// Replaces __shfl_xor (ds_swizzle -> LDS pipe) with DPP adds + gfx950
// v_permlane{16,32}_swap_b32.  Row-rotate levels scramble WHICH lane holds
// which partial group, but every writer lane still holds a disjoint full
// cover, and all consumers sum over all writers -> order-only change.
#define DPP_XOR1 0xB1   // quad_perm(1,0,3,2)
#define DPP_XOR2 0x4E   // quad_perm(2,3,0,1)
#define DPP_ROR4 0x124  // row_ror:4  (preserves lane mod 4 -> oq-safe)
#define DPP_ROR8 0x128  // row_ror:8
template<int CTRL>
__device__ __forceinline__ float dpp_add(float v) {
    int d = __builtin_amdgcn_update_dpp(0, __float_as_int(v), CTRL, 0xf, 0xf, false);
    return v + __int_as_float(d);
}
__device__ __forceinline__ float p16_add(float v) {   // v + (value from lane^16)
    float a = v, b = v;
    asm("v_permlane16_swap_b32 %0, %1" : "+v"(a), "+v"(b));
    return a + b;
}
__device__ __forceinline__ float p32_add(float v) {   // v + (value from lane^32)
    float a = v, b = v;
    asm("v_permlane32_swap_b32 %0, %1" : "+v"(a), "+v"(b));
    return a + b;
}
__device__ __forceinline__ float wave_sum64(float v) {  // full-wave sum, all lanes
    v = dpp_add<DPP_XOR1>(v);
    v = dpp_add<DPP_XOR2>(v);
    v = dpp_add<DPP_ROR4>(v);
    v = dpp_add<DPP_ROR8>(v);
    v = p16_add(v);
    return p32_add(v);
}

// Swizzled 16-B-unit index for (row r, half h): bijection within each 128-B
// group, spreads consecutive-r b128 reads over all 8 bank groups (R5-verified).
__device__ __forceinline__ int sunit(int r, int h) {
    return (2 * r + h) ^ ((r >> 2) & 7);
}

// ---------------- Kernel 1: pack W (always) and optionally x to f16 pairs.
// Blocks < 720:   W fp32 [n][r][i][o] -> Wp [n][r][o][i/2]  (256 B / row)
// Blocks >= 720:  x fp32 [b][r][i]    -> Xp [b][r] uint4 (8 halves, 16 B)
extern "C" __global__ void __launch_bounds__(256)
pack_wx(const float* __restrict__ W, const float* __restrict__ x,
        unsigned int* __restrict__ Wp, uint4* __restrict__ Xp)
{
    const int blk = blockIdx.x;
    if (blk < 720) {
        const int tau = blk * 256 + threadIdx.x;           // one thread per (n,r,o)
        const int o = tau & 15;
        const int nr = tau >> 4;
        const float* __restrict__ src = W + (size_t)nr * 128 + o;
        uint4 u;
        u.x = pkrtz(src[0],  src[16]);    // (i0,i1)
        u.y = pkrtz(src[32], src[48]);    // (i2,i3)
        u.z = pkrtz(src[64], src[80]);    // (i4,i5)
        u.w = pkrtz(src[96], src[112]);   // (i6,i7)
        *(uint4*)(Wp + (size_t)tau * 4) = u;
    } else {
        const int idx = (blk - 720) * 256 + threadIdx.x;   // one thread per (b,r)
        const float4 a = *(const float4*)(x + (size_t)idx * 8);
        const float4 b = *(const float4*)(x + (size_t)idx * 8 + 4);
        uint4 u;
        u.x = pkrtz(a.x, a.y);
        u.y = pkrtz(a.z, a.w);
        u.z = pkrtz(b.x, b.y);
        u.w = pkrtz(b.z, b.w);
        Xp[idx] = u;
    }
}

// ---------------- Main: 512 threads per (n, b-pair), f16 everywhere.
// v15 == v10 (R1-verified: 68.6 us main, absmax 0.0039) resubmitted unchanged
// as a control after v11-v14 all failed with inexplicable absmax 0.7-1.5.
// Structure: (1) DPP/permlane reductions on the VALU pipe; (2) Phase A
// ping-pong register prefetch; (3) x consumed pre-packed f16 (XP=true);
// (4) s-vector read as 4x ds_read_b128 into registers; (5) colsum finish
// done by one full wave per half.
template<bool XP>
__global__ void __launch_bounds__(512, 4)
capsule_routing_v15(const float* __restrict__ x,
                    const unsigned int* __restrict__ Wp,
                    const uint4* __restrict__ Xp,
                    float* __restrict__ out)
{
    __shared__ __align__(16) unsigned int pbuf[2 * R_ROUTES * 8]; // 73728 B priors
    __shared__ __align__(16) float wred[16 * 16];                 // 1024 B
    __shared__ __align__(16) float red[2 * 32 * 20];              // 5120 B
    __shared__ float sred[2 * 4];
    __shared__ __align__(16) float sv[2 * 16];

    const int blk = blockIdx.x;                      // n-major: Wp[n] L2-resident
    const int n = blk >> 8;
    const int bp = blk & 255;
    const int t = threadIdx.x;

    const unsigned int* __restrict__ Wn = Wp + (size_t)n * (R_ROUTES * 64);

    // ---------------- Phase A: priors (dot2) + pass-0 colsums, prefetched
    float cs[2][4] = {{0.f, 0.f, 0.f, 0.f}, {0.f, 0.f, 0.f, 0.f}};
    {
        const int q = t >> 2;                        // 0..127
        const int oq = t & 3;
        const int subw = (oq & 1) * 2;
        const int hq = oq >> 1;

        const float* __restrict__ x0 = x + (size_t)(2 * bp) * (R_ROUTES * CIN);
        const float* __restrict__ x1 = x0 + R_ROUTES * CIN;
        const uint4* __restrict__ xq0 = Xp + (size_t)(2 * bp) * R_ROUTES;
        const uint4* __restrict__ xq1 = xq0 + R_ROUTES;

        uint4 wA0, wA1, wA2, wA3, wB0, wB1, wB2, wB3;
        uint4 xA0, xA1, xB0, xB1;                    // packed h2 x rows (b0,b1)
        float4 gA0, gA1, gA2, gA3, gB0, gB1, gB2, gB3; // fallback raw x

        auto loadW = [&](int it, uint4& a0, uint4& a1, uint4& a2, uint4& a3) {
            const unsigned int* wb = Wn + (size_t)(it * 128 + q) * 64 + oq * 4;
            a0 = *(const uint4*)(wb + 0);            // o = oq
            a1 = *(const uint4*)(wb + 16);           // o = oq+4
            a2 = *(const uint4*)(wb + 32);           // o = oq+8
            a3 = *(const uint4*)(wb + 48);           // o = oq+12
        };
        auto loadX = [&](int it, uint4& a, uint4& b,
                         float4& g0, float4& g1, float4& g2, float4& g3) {
            const int r = it * 128 + q;
            if constexpr (XP) {
                a = xq0[r];
                b = xq1[r];
            } else {
                g0 = *(const float4*)(x0 + r * 8);
                g1 = *(const float4*)(x0 + r * 8 + 4);
                g2 = *(const float4*)(x1 + r * 8);
                g3 = *(const float4*)(x1 + r * 8 + 4);
            }
        };
        auto packX = [&](uint4& a, uint4& b,
                         float4 g0, float4 g1, float4 g2, float4 g3) {
            if constexpr (!XP) {
                a.x = pkrtz(g0.x, g0.y); a.y = pkrtz(g0.z, g0.w);
                a.z = pkrtz(g1.x, g1.y); a.w = pkrtz(g1.z, g1.w);
                b.x = pkrtz(g2.x, g2.y); b.y = pkrtz(g2.z, g2.w);
                b.z = pkrtz(g3.x, g3.y); b.w = pkrtz(g3.z, g3.w);
            }
        };
        auto compute = [&](int it, uint4 w0, uint4 w1, uint4 w2, uint4 w3,
                           uint4 xa, uint4 xb) {
            const int r = it * 128 + q;
            {   // batch 0
                const float p0 = dot2(w0.w, xa.w, dot2(w0.z, xa.z, dot2(w0.y, xa.y, dot2(w0.x, xa.x, 0.f))));
                const float p1 = dot2(w1.w, xa.w, dot2(w1.z, xa.z, dot2(w1.y, xa.y, dot2(w1.x, xa.x, 0.f))));
                const float p2 = dot2(w2.w, xa.w, dot2(w2.z, xa.z, dot2(w2.y, xa.y, dot2(w2.x, xa.x, 0.f))));
                const float p3 = dot2(w3.w, xa.w, dot2(w3.z, xa.z, dot2(w3.y, xa.y, dot2(w3.x, xa.x, 0.f))));
                cs[0][0] += p0; cs[0][1] += p1; cs[0][2] += p2; cs[0][3] += p3;
                uint2 u; u.x = pkrtz(p0, p1); u.y = pkrtz(p2, p3);
                *(uint2*)(pbuf + sunit(r, hq) * 4 + subw) = u;
            }
            {   // batch 1
                const float p0 = dot2(w0.w, xb.w, dot2(w0.z, xb.z, dot2(w0.y, xb.y, dot2(w0.x, xb.x, 0.f))));
                const float p1 = dot2(w1.w, xb.w, dot2(w1.z, xb.z, dot2(w1.y, xb.y, dot2(w1.x, xb.x, 0.f))));
                const float p2 = dot2(w2.w, xb.w, dot2(w2.z, xb.z, dot2(w2.y, xb.y, dot2(w2.x, xb.x, 0.f))));
                const float p3 = dot2(w3.w, xb.w, dot2(w3.z, xb.z, dot2(w3.y, xb.y, dot2(w3.x, xb.x, 0.f))));
                cs[1][0] += p0; cs[1][1] += p1; cs[1][2] += p2; cs[1][3] += p3;
                uint2 u; u.x = pkrtz(p0, p1); u.y = pkrtz(p2, p3);
                *(uint2*)(pbuf + R_ROUTES * 8 + sunit(r, hq) * 4 + subw) = u;
            }
        };

        // ping-pong: loads for it+1 issue before compute(it) -> ~1 full
        // compute stage (x4 waves) of latency cover, no rotation movs.
        loadW(0, wA0, wA1, wA2, wA3);
        loadX(0, xA0, xA1, gA0, gA1, gA2, gA3);
        #pragma unroll 1
        for (int it = 0; it < 8; it += 2) {
            loadW(it + 1, wB0, wB1, wB2, wB3);
            loadX(it + 1, xB0, xB1, gB0, gB1, gB2, gB3);
            packX(xA0, xA1, gA0, gA1, gA2, gA3);
            compute(it, wA0, wA1, wA2, wA3, xA0, xA1);
            loadW(it + 2, wA0, wA1, wA2, wA3);
            loadX(it + 2, xA0, xA1, gA0, gA1, gA2, gA3);
            packX(xB0, xB1, gB0, gB1, gB2, gB3);
            compute(it + 1, wB0, wB1, wB2, wB3, xB0, xB1);
        }
        packX(xA0, xA1, gA0, gA1, gA2, gA3);
        compute(8, wA0, wA1, wA2, wA3, xA0, xA1);

        // pass-0 reduce over same-oq lanes: 4 levels, all on VALU
        #pragma unroll
        for (int b = 0; b < 2; ++b)
            #pragma unroll
            for (int j = 0; j < 4; ++j) {
                float v = cs[b][j];
                v = dpp_add<DPP_ROR4>(v);
                v = dpp_add<DPP_ROR8>(v);
                v = p16_add(v);
                v = p32_add(v);
                cs[b][j] = v;
            }
        if ((t & 63) < 4) {                          // lane oq of each wave writes
            const int w = t >> 6;
            *(float4*)(wred + (w * 2 + 0) * 16 + 4 * oq) =
                make_float4(cs[0][0], cs[0][1], cs[0][2], cs[0][3]);
            *(float4*)(wred + (w * 2 + 1) * 16 + 4 * oq) =
                make_float4(cs[1][0], cs[1][1], cs[1][2], cs[1][3]);
        }
    }
    __syncthreads();                                 // barA1 (also pbuf ready)

    // ---------------- Phase B setup
    const int half = t >> 8;
    const int tt = t & 255;
    unsigned int* __restrict__ pb = pbuf + half * (R_ROUTES * 8);
    float* __restrict__ redh = red + half * (32 * 20);
    float* __restrict__ sredh = sred + half * 4;
    float* __restrict__ svh = sv + half * 16;        // permuted order end-to-end

    if (tt < 64) {                                   // one full wave per half
        const int k = tt & 15, wg = tt >> 4;
        float s = wred[(wg * 2 + half) * 16 + k] + wred[((wg + 4) * 2 + half) * 16 + k];
        s = p16_add(s);
        s = p32_add(s);
        if (tt < 16) svh[tt] = s * (1.0f / (float)R_ROUTES);
    }
    __syncthreads();                                 // barA2

    float4 s0 = *(const float4*)(svh + 0);
    float4 s1 = *(const float4*)(svh + 4);
    float4 s2 = *(const float4*)(svh + 8);
    float4 s3 = *(const float4*)(svh + 12);
    float sn = s0.x * s0.x;
    sn = fmaf(s0.y, s0.y, sn); sn = fmaf(s0.z, s0.z, sn); sn = fmaf(s0.w, s0.w, sn);
    sn = fmaf(s1.x, s1.x, sn); sn = fmaf(s1.y, s1.y, sn); sn = fmaf(s1.z, s1.z, sn);
    sn = fmaf(s1.w, s1.w, sn);
    sn = fmaf(s2.x, s2.x, sn); sn = fmaf(s2.y, s2.y, sn); sn = fmaf(s2.z, s2.z, sn);
    sn = fmaf(s2.w, s2.w, sn);
    sn = fmaf(s3.x, s3.x, sn); sn = fmaf(s3.y, s3.y, sn); sn = fmaf(s3.z, s3.z, sn);
    sn = fmaf(s3.w, s3.w, sn);
    float factor = sn / ((1.0f + sn) * sqrtf(sn));

    const int nr = (tt < 128) ? 5 : 4;               // wave-uniform
    float bl[5] = {0.f, 0.f, 0.f, 0.f, 0.f};

    // ---------------- passes 1..2: fused logit-update + exp + weighted sum
    #pragma unroll 1
    for (int pass = 1; pass < NUM_ROUNDS; ++pass) {
        unsigned int svp[8];
        svp[0] = pkrtz(s0.x, s0.y); svp[1] = pkrtz(s0.z, s0.w);
        svp[2] = pkrtz(s1.x, s1.y); svp[3] = pkrtz(s1.z, s1.w);
        svp[4] = pkrtz(s2.x, s2.y); svp[5] = pkrtz(s2.z, s2.w);
        svp[6] = pkrtz(s3.x, s3.y); svp[7] = pkrtz(s3.z, s3.w);
        float acc[16];
        #pragma unroll
        for (int o = 0; o < 16; ++o) acc[o] = 0.f;
        float es = 0.f;

        #pragma unroll
        for (int k = 0; k < 5; ++k) {
            if (k < nr) {
                const int r = tt + (k << 8);
                const uint4 a = *(const uint4*)(pb + sunit(r, 0) * 4);
                const uint4 c = *(const uint4*)(pb + sunit(r, 1) * 4);
                float d = 0.f;
                d = dot2(a.x, svp[0], d);
                d = dot2(a.y, svp[1], d);
                d = dot2(a.z, svp[2], d);
                d = dot2(a.w, svp[3], d);
                d = dot2(c.x, svp[4], d);
                d = dot2(c.y, svp[5], d);
                d = dot2(c.z, svp[6], d);
                d = dot2(c.w, svp[7], d);
                bl[k] = fmaf(factor, d, bl[k]);
                const float e = __expf(bl[k]);
                es += e;
                acc[0]  = fmaf(e, f_lo(a.x), acc[0]);
                acc[1]  = fmaf(e, f_hi(a.x), acc[1]);
                acc[2]  = fmaf(e, f_lo(a.y), acc[2]);
                acc[3]  = fmaf(e, f_hi(a.y), acc[3]);
                acc[4]  = fmaf(e, f_lo(a.z), acc[4]);
                acc[5]  = fmaf(e, f_hi(a.z), acc[5]);
                acc[6]  = fmaf(e, f_lo(a.w), acc[6]);
                acc[7]  = fmaf(e, f_hi(a.w), acc[7]);
                acc[8]  = fmaf(e, f_lo(c.x), acc[8]);
                acc[9]  = fmaf(e, f_hi(c.x), acc[9]);
                acc[10] = fmaf(e, f_lo(c.y), acc[10]);
                acc[11] = fmaf(e, f_hi(c.y), acc[11]);
                acc[12] = fmaf(e, f_lo(c.z), acc[12]);
                acc[13] = fmaf(e, f_hi(c.z), acc[13]);
                acc[14] = fmaf(e, f_lo(c.w), acc[14]);
                acc[15] = fmaf(e, f_hi(c.w), acc[15]);
            }
        }
        es = wave_sum64(es);
        if ((t & 63) == 0) sredh[tt >> 6] = es;

        // 8-lane pre-reduce on VALU (DPP) -> 32 LDS writers per half
        #pragma unroll
        for (int o = 0; o < 16; ++o) {
            float v = acc[o];
            v = dpp_add<DPP_XOR1>(v);
            v = dpp_add<DPP_XOR2>(v);
            v = dpp_add<DPP_ROR4>(v);                // writers get disjoint 8-covers
            acc[o] = v;
        }
        if ((tt & 7) == 0) {
            float* dst = redh + (tt >> 3) * 20;      // 80-B stride: conflict-free b128
            *(float4*)(dst + 0)  = make_float4(acc[0],  acc[1],  acc[2],  acc[3]);
            *(float4*)(dst + 4)  = make_float4(acc[4],  acc[5],  acc[6],  acc[7]);
            *(float4*)(dst + 8)  = make_float4(acc[8],  acc[9],  acc[10], acc[11]);
            *(float4*)(dst + 12) = make_float4(acc[12], acc[13], acc[14], acc[15]);
        }
        __syncthreads();                             // bar1

        if (tt < 64) {                               // one full wave per half
            const int k = tt & 15, wg = tt >> 4;
            float s = 0.f;
            #pragma unroll
            for (int i = 0; i < 8; ++i) s += redh[(wg * 8 + i) * 20 + k];
            s = p16_add(s);
            s = p32_add(s);
            if (tt < 16) {
                const float Z = sredh[0] + sredh[1] + sredh[2] + sredh[3];
                svh[tt] = s / Z;
            }
        }
        __syncthreads();                             // bar2

        s0 = *(const float4*)(svh + 0);
        s1 = *(const float4*)(svh + 4);
        s2 = *(const float4*)(svh + 8);
        s3 = *(const float4*)(svh + 12);
        sn = s0.x * s0.x;
        sn = fmaf(s0.y, s0.y, sn); sn = fmaf(s0.z, s0.z, sn); sn = fmaf(s0.w, s0.w, sn);
        sn = fmaf(s1.x, s1.x, sn); sn = fmaf(s1.y, s1.y, sn); sn = fmaf(s1.z, s1.z, sn);
        sn = fmaf(s1.w, s1.w, sn);
        sn = fmaf(s2.x, s2.x, sn); sn = fmaf(s2.y, s2.y, sn); sn = fmaf(s2.z, s2.z, sn);
        sn = fmaf(s2.w, s2.w, sn);
        sn = fmaf(s3.x, s3.x, sn); sn = fmaf(s3.y, s3.y, sn); sn = fmaf(s3.z, s3.z, sn);
        sn = fmaf(s3.w, s3.w, sn);
        factor = sn / ((1.0f + sn) * sqrtf(sn));
    }

    if (tt < 16) {
        const int o = (tt >> 2) + ((tt & 3) << 2);   // un-permute slot -> o
        out[((size_t)n * BATCH + 2 * bp + half) * COUT + o] = factor * svh[tt];
    }
}

extern "C" void kernel_launch(void* const* d_in, const int* in_sizes, int n_in,
                              void* d_out, int out_size, void* d_ws, size_t ws_size,
                              hipStream_t stream) {
    const float* x = (const float*)d_in[0];   // [512, 1152, 8] fp32
    const float* W = (const float*)d_in[1];   // [10, 1152, 8, 16] fp32
    float* out = (float*)d_out;               // [10, 512, 1, 1, 16] fp32

    unsigned int* Wp = (unsigned int*)d_ws;   // 2,949,120 B f16-packed W
    const size_t WPB = (size_t)NCAPS * R_ROUTES * COUT * 16;          // 2,949,120
    const size_t XPB = (size_t)BATCH * R_ROUTES * 16;                 // 9,437,184
    uint4* Xp = (uint4*)((char*)d_ws + WPB);

    if (ws_size >= WPB + XPB) {
        pack_wx<<<dim3(720 + 2304), dim3(256), 0, stream>>>(W, x, Wp, Xp);
        capsule_routing_v15<true><<<dim3(NCAPS * (BATCH / 2)), dim3(512), 0, stream>>>(x, Wp, Xp, out);
    } else {
        pack_wx<<<dim3(720), dim3(256), 0, stream>>>(W, x, Wp, Xp);
        capsule_routing_v15<false><<<dim3(NCAPS * (BATCH / 2)), dim3(512), 0, stream>>>(x, Wp, Xp, out);
    }
}